// Round 1
// baseline (138.159 us; speedup 1.0000x reference)
//
#include <hip/hip_runtime.h>
#include <cstdint>
#include <cstddef>

#define B_ 4
#define L_ 4096
#define E_ 1024
#define H_ 16
#define D_ 64
#define BH_ (B_*H_)
#define STATE_ (65*64)   // rows 0..63 = kv[d][e], row 64 = ksum[d]

__device__ __forceinline__ float sigk(float x) {
    // sigmoid(0.6053*x - 4.102) = 1/(1+exp(4.102 - 0.6053*x))
    return __builtin_amdgcn_rcpf(1.0f + __expf(4.102f - 0.6053f * x));
}

// ---------------- Kernel 1: partial KV state per (b,h,chunk) ----------------
__global__ void __launch_bounds__(256) kv_partial_kernel(
    const float* __restrict__ K, const float* __restrict__ V,
    float* __restrict__ partial, int nch, int rowsPerCh)
{
    __shared__ float Kt[64][68];   // stride 68: 16B-aligned rows, conflict-light
    __shared__ float Vt[64][68];
    const int blk = blockIdx.x;
    const int ch  = blk % nch;
    const int bh  = blk / nch;
    const int b = bh / H_, h = bh % H_;
    const int tid = threadIdx.x;
    const int rr  = tid >> 4;          // 0..15 (load row group)
    const int c4  = (tid & 15) << 2;   // load col (float4)
    const int d0  = (tid >> 4) << 2;   // compute: 4 d's
    const int e0  = (tid & 15) << 2;   // compute: 4 e's

    float acc[4][4] = {{0.f}};
    float ks[4] = {0.f, 0.f, 0.f, 0.f};

    const int k0   = ch * rowsPerCh;
    const int nsub = rowsPerCh >> 6;
    for (int t = 0; t < nsub; ++t) {
        const int krow0 = k0 + (t << 6);
        #pragma unroll
        for (int i = 0; i < 4; ++i) {
            const int row = rr + (i << 4);
            const size_t g = ((size_t)(b * L_ + krow0 + row)) * E_ + h * D_ + c4;
            const float4 kk = *(const float4*)(K + g);
            const float4 vv = *(const float4*)(V + g);
            float4 pk;
            pk.x = sigk(kk.x); pk.y = sigk(kk.y); pk.z = sigk(kk.z); pk.w = sigk(kk.w);
            *(float4*)&Kt[row][c4] = pk;
            *(float4*)&Vt[row][c4] = vv;
        }
        __syncthreads();
        #pragma unroll 8
        for (int k = 0; k < 64; ++k) {
            const float4 a = *(const float4*)&Kt[k][d0];
            const float4 v = *(const float4*)&Vt[k][e0];
            const float av[4] = {a.x, a.y, a.z, a.w};
            const float bv[4] = {v.x, v.y, v.z, v.w};
            #pragma unroll
            for (int i = 0; i < 4; ++i)
                #pragma unroll
                for (int j = 0; j < 4; ++j)
                    acc[i][j] = fmaf(av[i], bv[j], acc[i][j]);
            if (e0 == 0) {
                #pragma unroll
                for (int i = 0; i < 4; ++i) ks[i] += av[i];
            }
        }
        __syncthreads();
    }

    const size_t pbase = ((size_t)ch * BH_ + bh) * STATE_;
    #pragma unroll
    for (int i = 0; i < 4; ++i) {
        float4 o;
        o.x = acc[i][0]; o.y = acc[i][1]; o.z = acc[i][2]; o.w = acc[i][3];
        *(float4*)(partial + pbase + (size_t)(d0 + i) * 64 + e0) = o;
    }
    if (e0 == 0) {
        #pragma unroll
        for (int i = 0; i < 4; ++i) partial[pbase + 4096 + d0 + i] = ks[i];
    }
}

// ---------------- Kernel 2: reduce partials -> final KV state ----------------
__global__ void __launch_bounds__(256) kv_reduce_kernel(
    const float* __restrict__ partial, float* __restrict__ kv, int nch)
{
    const int total = BH_ * STATE_;
    const int idx = blockIdx.x * 256 + threadIdx.x;
    if (idx >= total) return;
    float s = 0.f;
    for (int c = 0; c < nch; ++c) s += partial[(size_t)c * total + idx];
    kv[idx] = s;
}

// ---------------- Kernel 3: out = (phiQ @ kv) / (phiQ @ ksum) ----------------
__global__ void __launch_bounds__(256) attn_out_kernel(
    const float* __restrict__ Q, const float* __restrict__ kv,
    float* __restrict__ out)
{
    __shared__ float kvs[STATE_];
    const int bh = blockIdx.x >> 3;          // 8 q-tiles of 512 rows per (b,h)
    const int qt = blockIdx.x & 7;
    const int b = bh / H_, h = bh % H_;
    const int tid = threadIdx.x;
    {
        const float4* src = (const float4*)(kv + (size_t)bh * STATE_);
        float4* dst = (float4*)kvs;
        for (int i = tid; i < STATE_ / 4; i += 256) dst[i] = src[i];
    }
    __syncthreads();

    const int r0 = qt * 512 + tid;
    const int r1 = r0 + 256;
    const float4* q0 = (const float4*)(Q + ((size_t)b * L_ + r0) * E_ + h * D_);
    const float4* q1 = (const float4*)(Q + ((size_t)b * L_ + r1) * E_ + h * D_);

    float4 acc0[16], acc1[16];
    #pragma unroll
    for (int j = 0; j < 16; ++j) {
        acc0[j] = make_float4(0.f, 0.f, 0.f, 0.f);
        acc1[j] = make_float4(0.f, 0.f, 0.f, 0.f);
    }
    float den0 = 0.f, den1 = 0.f;

    for (int jj = 0; jj < 16; ++jj) {
        const float4 a = q0[jj];
        const float4 c = q1[jj];
        const float p0[4] = {sigk(a.x), sigk(a.y), sigk(a.z), sigk(a.w)};
        const float p1[4] = {sigk(c.x), sigk(c.y), sigk(c.z), sigk(c.w)};
        const int dbase = jj << 2;
        #pragma unroll
        for (int i = 0; i < 4; ++i) {
            const float kd = kvs[4096 + dbase + i];  // broadcast (wave-uniform)
            den0 = fmaf(p0[i], kd, den0);
            den1 = fmaf(p1[i], kd, den1);
        }
        #pragma unroll
        for (int i = 0; i < 4; ++i) {
            const float4* row = (const float4*)(kvs + (size_t)(dbase + i) * 64);
            const float s0 = p0[i], s1 = p1[i];
            #pragma unroll
            for (int j = 0; j < 16; ++j) {
                const float4 v = row[j];             // broadcast (wave-uniform)
                acc0[j].x = fmaf(s0, v.x, acc0[j].x);
                acc0[j].y = fmaf(s0, v.y, acc0[j].y);
                acc0[j].z = fmaf(s0, v.z, acc0[j].z);
                acc0[j].w = fmaf(s0, v.w, acc0[j].w);
                acc1[j].x = fmaf(s1, v.x, acc1[j].x);
                acc1[j].y = fmaf(s1, v.y, acc1[j].y);
                acc1[j].z = fmaf(s1, v.z, acc1[j].z);
                acc1[j].w = fmaf(s1, v.w, acc1[j].w);
            }
        }
    }

    const float inv0 = __builtin_amdgcn_rcpf(den0);
    const float inv1 = __builtin_amdgcn_rcpf(den1);
    float4* o0 = (float4*)(out + ((size_t)b * L_ + r0) * E_ + h * D_);
    float4* o1 = (float4*)(out + ((size_t)b * L_ + r1) * E_ + h * D_);
    #pragma unroll
    for (int j = 0; j < 16; ++j) {
        o0[j] = make_float4(acc0[j].x * inv0, acc0[j].y * inv0,
                            acc0[j].z * inv0, acc0[j].w * inv0);
        o1[j] = make_float4(acc1[j].x * inv1, acc1[j].y * inv1,
                            acc1[j].z * inv1, acc1[j].w * inv1);
    }
}

extern "C" void kernel_launch(void* const* d_in, const int* in_sizes, int n_in,
                              void* d_out, int out_size, void* d_ws, size_t ws_size,
                              hipStream_t stream) {
    const float* Q = (const float*)d_in[0];
    const float* K = (const float*)d_in[1];
    const float* V = (const float*)d_in[2];
    float* out = (float*)d_out;

    float* kv      = (float*)d_ws;                 // BH_*STATE_ floats (~1 MiB)
    float* partial = kv + (size_t)BH_ * STATE_;    // nch*BH_*STATE_ floats

    int nch = 16;
    while (nch > 1 &&
           (size_t)(1 + nch) * BH_ * STATE_ * sizeof(float) > ws_size)
        nch >>= 1;
    const int rowsPerCh = L_ / nch;

    hipLaunchKernelGGL(kv_partial_kernel, dim3(BH_ * nch), dim3(256), 0, stream,
                       K, V, partial, nch, rowsPerCh);

    const int total = BH_ * STATE_;
    hipLaunchKernelGGL(kv_reduce_kernel, dim3((total + 255) / 256), dim3(256), 0, stream,
                       partial, kv, nch);

    hipLaunchKernelGGL(attn_out_kernel, dim3(BH_ * (L_ / 512)), dim3(256), 0, stream,
                       Q, kv, out);
}

// Round 2
// 123.327 us; speedup vs baseline: 1.1203x; 1.1203x over previous
//
#include <hip/hip_runtime.h>
#include <cstdint>
#include <cstddef>

#define B_ 4
#define L_ 4096
#define E_ 1024
#define H_ 16
#define D_ 64
#define BH_ (B_*H_)
#define STATE_ (65*64)   // rows 0..63 = kv[d][e], row 64 = ksum[d]

__device__ __forceinline__ float sigk(float x) {
    // sigmoid(0.6053*x - 4.102) = 1/(1+exp(4.102 - 0.6053*x))
    return __builtin_amdgcn_rcpf(1.0f + __expf(4.102f - 0.6053f * x));
}

// ---------------- Kernel 1: partial KV state per (b,h,chunk) ----------------
__global__ void __launch_bounds__(256) kv_partial_kernel(
    const float* __restrict__ K, const float* __restrict__ V,
    float* __restrict__ partial, int nch, int rowsPerCh)
{
    __shared__ float Kt[64][68];   // stride 68: 16B-aligned rows, conflict-light
    __shared__ float Vt[64][68];
    const int blk = blockIdx.x;
    const int ch  = blk % nch;
    const int bh  = blk / nch;
    const int b = bh / H_, h = bh % H_;
    const int tid = threadIdx.x;
    const int rr  = tid >> 4;          // 0..15 (load row group)
    const int c4  = (tid & 15) << 2;   // load col (float4)
    const int d0  = (tid >> 4) << 2;   // compute: 4 d's
    const int e0  = (tid & 15) << 2;   // compute: 4 e's

    float acc[4][4] = {{0.f}};
    float ks[4] = {0.f, 0.f, 0.f, 0.f};

    const int k0   = ch * rowsPerCh;
    const int nsub = rowsPerCh >> 6;
    for (int t = 0; t < nsub; ++t) {
        const int krow0 = k0 + (t << 6);
        #pragma unroll
        for (int i = 0; i < 4; ++i) {
            const int row = rr + (i << 4);
            const size_t g = ((size_t)(b * L_ + krow0 + row)) * E_ + h * D_ + c4;
            const float4 kk = *(const float4*)(K + g);
            const float4 vv = *(const float4*)(V + g);
            float4 pk;
            pk.x = sigk(kk.x); pk.y = sigk(kk.y); pk.z = sigk(kk.z); pk.w = sigk(kk.w);
            *(float4*)&Kt[row][c4] = pk;
            *(float4*)&Vt[row][c4] = vv;
        }
        __syncthreads();
        #pragma unroll 8
        for (int k = 0; k < 64; ++k) {
            const float4 a = *(const float4*)&Kt[k][d0];
            const float4 v = *(const float4*)&Vt[k][e0];
            const float av[4] = {a.x, a.y, a.z, a.w};
            const float bv[4] = {v.x, v.y, v.z, v.w};
            #pragma unroll
            for (int i = 0; i < 4; ++i)
                #pragma unroll
                for (int j = 0; j < 4; ++j)
                    acc[i][j] = fmaf(av[i], bv[j], acc[i][j]);
            if (e0 == 0) {
                #pragma unroll
                for (int i = 0; i < 4; ++i) ks[i] += av[i];
            }
        }
        __syncthreads();
    }

    const size_t pbase = ((size_t)ch * BH_ + bh) * STATE_;
    #pragma unroll
    for (int i = 0; i < 4; ++i) {
        float4 o;
        o.x = acc[i][0]; o.y = acc[i][1]; o.z = acc[i][2]; o.w = acc[i][3];
        *(float4*)(partial + pbase + (size_t)(d0 + i) * 64 + e0) = o;
    }
    if (e0 == 0) {
        #pragma unroll
        for (int i = 0; i < 4; ++i) partial[pbase + 4096 + d0 + i] = ks[i];
    }
}

// ---------------- Kernel 2: reduce partials -> final KV state ----------------
__global__ void __launch_bounds__(256) kv_reduce_kernel(
    const float* __restrict__ partial, float* __restrict__ kv, int nch)
{
    const int total = BH_ * STATE_;
    const int idx = blockIdx.x * 256 + threadIdx.x;
    if (idx >= total) return;
    float s = 0.f;
    for (int c = 0; c < nch; ++c) s += partial[(size_t)c * total + idx];
    kv[idx] = s;
}

// ---------------- Kernel 3: out = (phiQ @ kv) / (phiQ @ ksum) ----------------
// Each block: one (b,h) and a 64-row q-tile. Each thread: 1 q-row x 16 e-cols.
// Lane e-mapping e = (tid&3)*4 + 16*j makes each 4-lane group's global store
// 64B contiguous, and LDS kv-row reads are 4 distinct addrs x 16-lane
// broadcast (banks 0..15) -> conflict-free.
__global__ void __launch_bounds__(256) attn_out_kernel(
    const float* __restrict__ Q, const float* __restrict__ kv,
    float* __restrict__ out)
{
    __shared__ float kvs[STATE_];
    const int bh = blockIdx.x >> 6;          // 64 q-tiles of 64 rows per (b,h)
    const int qt = blockIdx.x & 63;
    const int b = bh / H_, h = bh % H_;
    const int tid = threadIdx.x;
    {
        const float4* src = (const float4*)(kv + (size_t)bh * STATE_);
        float4* dst = (float4*)kvs;
        for (int i = tid; i < STATE_ / 4; i += 256) dst[i] = src[i];
    }
    __syncthreads();

    const int rq  = tid >> 2;            // 0..63: q-row within tile
    const int el  = (tid & 3) << 2;      // 0,4,8,12: e sub-offset
    const int row = qt * 64 + rq;
    const float4* qp = (const float4*)(Q + ((size_t)b * L_ + row) * E_ + h * D_);

    float4 acc[4];
    #pragma unroll
    for (int j = 0; j < 4; ++j) acc[j] = make_float4(0.f, 0.f, 0.f, 0.f);
    float den = 0.f;

    #pragma unroll 4
    for (int jj = 0; jj < 16; ++jj) {
        const float4 a = qp[jj];
        const float p[4] = {sigk(a.x), sigk(a.y), sigk(a.z), sigk(a.w)};
        const int dbase = jj << 2;
        #pragma unroll
        for (int i = 0; i < 4; ++i) {
            const float s = p[i];
            den = fmaf(s, kvs[4096 + dbase + i], den);
            const float* krow = kvs + (size_t)(dbase + i) * 64 + el;
            #pragma unroll
            for (int j = 0; j < 4; ++j) {
                const float4 v = *(const float4*)(krow + (j << 4));
                acc[j].x = fmaf(s, v.x, acc[j].x);
                acc[j].y = fmaf(s, v.y, acc[j].y);
                acc[j].z = fmaf(s, v.z, acc[j].z);
                acc[j].w = fmaf(s, v.w, acc[j].w);
            }
        }
    }

    const float inv = __builtin_amdgcn_rcpf(den);
    float* op = out + ((size_t)b * L_ + row) * E_ + h * D_ + el;
    #pragma unroll
    for (int j = 0; j < 4; ++j) {
        float4 o;
        o.x = acc[j].x * inv; o.y = acc[j].y * inv;
        o.z = acc[j].z * inv; o.w = acc[j].w * inv;
        *(float4*)(op + (j << 4)) = o;
    }
}

extern "C" void kernel_launch(void* const* d_in, const int* in_sizes, int n_in,
                              void* d_out, int out_size, void* d_ws, size_t ws_size,
                              hipStream_t stream) {
    const float* Q = (const float*)d_in[0];
    const float* K = (const float*)d_in[1];
    const float* V = (const float*)d_in[2];
    float* out = (float*)d_out;

    float* kv      = (float*)d_ws;                 // BH_*STATE_ floats (~1 MiB)
    float* partial = kv + (size_t)BH_ * STATE_;    // nch*BH_*STATE_ floats

    int nch = 32;
    while (nch > 1 &&
           (size_t)(1 + nch) * BH_ * STATE_ * sizeof(float) > ws_size)
        nch >>= 1;
    const int rowsPerCh = L_ / nch;

    hipLaunchKernelGGL(kv_partial_kernel, dim3(BH_ * nch), dim3(256), 0, stream,
                       K, V, partial, nch, rowsPerCh);

    const int total = BH_ * STATE_;
    hipLaunchKernelGGL(kv_reduce_kernel, dim3((total + 255) / 256), dim3(256), 0, stream,
                       partial, kv, nch);

    hipLaunchKernelGGL(attn_out_kernel, dim3(BH_ * (L_ / 64)), dim3(256), 0, stream,
                       Q, kv, out);
}

// Round 3
// 119.078 us; speedup vs baseline: 1.1602x; 1.0357x over previous
//
#include <hip/hip_runtime.h>
#include <cstdint>
#include <cstddef>

#define B_ 4
#define L_ 4096
#define E_ 1024
#define H_ 16
#define D_ 64
#define BH_ (B_*H_)
#define STATE_ (65*64)   // rows 0..63 = kv[d][e], row 64 = ksum[d]
#define NCH_ 8
#define RPC_ (L_/NCH_)    // 512 rows per chunk
#define TROWS_ 128        // rows per staging round
#define NR_ (RPC_/TROWS_) // 4 rounds
#define LDK_ 68           // padded LDS row stride (floats)

__device__ __forceinline__ float sigk(float x) {
    // sigmoid(0.6053*x - 4.102) = 1/(1+exp(4.102 - 0.6053*x))
    return __builtin_amdgcn_rcpf(1.0f + __expf(4.102f - 0.6053f * x));
}

// ---------------- Kernel 1: partial KV state per (b,h,chunk) ----------------
// 512 blocks (2/CU). Each wave computes the full 64x64 outer product (8x8 per
// lane) over its private 32-row k-subrange of each 128-row LDS tile.
// Reg-staged prefetch: next tile's global loads are issued before compute and
// land during the ~4096-cycle FMA phase.
__global__ void __launch_bounds__(256, 2) kv_partial_kernel(
    const float* __restrict__ K, const float* __restrict__ V,
    float* __restrict__ partial)
{
    __shared__ float lds[2 * TROWS_ * LDK_];   // Kt then Vt; reused for reduce
    float* Kt = lds;
    float* Vt = lds + TROWS_ * LDK_;

    const int ch = blockIdx.x % NCH_;
    const int bh = blockIdx.x / NCH_;
    const int b = bh / H_, h = bh % H_;
    const int tid = threadIdx.x;
    const int w = tid >> 6, lane = tid & 63;
    const int rr = tid >> 4, c4 = (tid & 15) << 2;   // staging: row-group, col
    const int d0 = (lane >> 3) << 3;                 // compute: 8 d's
    const int e0 = (lane & 7) << 3;                  // compute: 8 e's

    const size_t gbase = (size_t)(b * L_ + ch * RPC_) * E_ + h * D_ + c4;

    float4 kreg[8], vreg[8];
    float acc[8][8];
    #pragma unroll
    for (int i = 0; i < 8; ++i)
        #pragma unroll
        for (int j = 0; j < 8; ++j) acc[i][j] = 0.f;
    float ks[8] = {0.f,0.f,0.f,0.f,0.f,0.f,0.f,0.f};

    // prologue: load round 0 into registers
    #pragma unroll
    for (int i = 0; i < 8; ++i) {
        const size_t g = gbase + (size_t)(rr + (i << 4)) * E_;
        kreg[i] = *(const float4*)(K + g);
        vreg[i] = *(const float4*)(V + g);
    }

    for (int t = 0; t < NR_; ++t) {
        // write staged regs (sigmoid on K) to LDS
        #pragma unroll
        for (int i = 0; i < 8; ++i) {
            const int row = rr + (i << 4);
            float4 pk;
            pk.x = sigk(kreg[i].x); pk.y = sigk(kreg[i].y);
            pk.z = sigk(kreg[i].z); pk.w = sigk(kreg[i].w);
            *(float4*)(Kt + row * LDK_ + c4) = pk;
            *(float4*)(Vt + row * LDK_ + c4) = vreg[i];
        }
        __syncthreads();
        // issue next round's loads; they fly during compute below
        if (t + 1 < NR_) {
            #pragma unroll
            for (int i = 0; i < 8; ++i) {
                const size_t g = gbase +
                    (size_t)((t + 1) * TROWS_ + rr + (i << 4)) * E_;
                kreg[i] = *(const float4*)(K + g);
                vreg[i] = *(const float4*)(V + g);
            }
        }
        // compute: this wave's 32-row k-subrange
        const float* kp = Kt + (w << 5) * LDK_ + d0;
        const float* vp = Vt + (w << 5) * LDK_ + e0;
        #pragma unroll 4
        for (int kk = 0; kk < 32; ++kk) {
            const float4 ka0 = *(const float4*)(kp);
            const float4 ka1 = *(const float4*)(kp + 4);
            const float4 vb0 = *(const float4*)(vp);
            const float4 vb1 = *(const float4*)(vp + 4);
            const float av[8] = {ka0.x,ka0.y,ka0.z,ka0.w,ka1.x,ka1.y,ka1.z,ka1.w};
            const float bv[8] = {vb0.x,vb0.y,vb0.z,vb0.w,vb1.x,vb1.y,vb1.z,vb1.w};
            #pragma unroll
            for (int i = 0; i < 8; ++i)
                #pragma unroll
                for (int j = 0; j < 8; ++j)
                    acc[i][j] = fmaf(av[i], bv[j], acc[i][j]);
            if (e0 == 0) {
                #pragma unroll
                for (int i = 0; i < 8; ++i) ks[i] += av[i];
            }
            kp += LDK_; vp += LDK_;
        }
        __syncthreads();
    }

    // reduce 4 per-wave partials via LDS (reuse tile buffer; compute is done)
    #pragma unroll
    for (int i = 0; i < 8; ++i) {
        float* dst = lds + (w << 12) + (d0 + i) * 64 + e0;
        *(float4*)(dst)     = make_float4(acc[i][0],acc[i][1],acc[i][2],acc[i][3]);
        *(float4*)(dst + 4) = make_float4(acc[i][4],acc[i][5],acc[i][6],acc[i][7]);
    }
    if (e0 == 0) {
        #pragma unroll
        for (int i = 0; i < 8; ++i) lds[16384 + (w << 6) + d0 + i] = ks[i];
    }
    __syncthreads();

    const size_t pbase = ((size_t)ch * BH_ + bh) * STATE_;
    #pragma unroll
    for (int i = 0; i < 4; ++i) {
        const int idx = (tid << 2) + (i << 10);     // coalesced float4 writes
        float4 s = *(const float4*)(lds + idx);
        #pragma unroll
        for (int ww = 1; ww < 4; ++ww) {
            const float4 p = *(const float4*)(lds + (ww << 12) + idx);
            s.x += p.x; s.y += p.y; s.z += p.z; s.w += p.w;
        }
        *(float4*)(partial + pbase + idx) = s;
    }
    if (tid < 64) {
        float s = 0.f;
        #pragma unroll
        for (int ww = 0; ww < 4; ++ww) s += lds[16384 + (ww << 6) + tid];
        partial[pbase + 4096 + tid] = s;
    }
}

// ---------------- Kernel 2: reduce partials -> final KV state ----------------
__global__ void __launch_bounds__(256) kv_reduce_kernel(
    const float* __restrict__ partial, float* __restrict__ kv)
{
    const int total = BH_ * STATE_;
    const int idx = blockIdx.x * 256 + threadIdx.x;
    if (idx >= total) return;
    float s = 0.f;
    #pragma unroll
    for (int c = 0; c < NCH_; ++c) s += partial[(size_t)c * total + idx];
    kv[idx] = s;
}

// ---------------- Kernel 3: out = (phiQ @ kv) / (phiQ @ ksum) ----------------
__global__ void __launch_bounds__(256) attn_out_kernel(
    const float* __restrict__ Q, const float* __restrict__ kv,
    float* __restrict__ out)
{
    __shared__ float kvs[STATE_];
    const int bh = blockIdx.x >> 6;          // 64 q-tiles of 64 rows per (b,h)
    const int qt = blockIdx.x & 63;
    const int b = bh / H_, h = bh % H_;
    const int tid = threadIdx.x;
    {
        const float4* src = (const float4*)(kv + (size_t)bh * STATE_);
        float4* dst = (float4*)kvs;
        for (int i = tid; i < STATE_ / 4; i += 256) dst[i] = src[i];
    }
    __syncthreads();

    const int rq  = tid >> 2;            // 0..63: q-row within tile
    const int el  = (tid & 3) << 2;      // 0,4,8,12: e sub-offset
    const int row = qt * 64 + rq;
    const float4* qp = (const float4*)(Q + ((size_t)b * L_ + row) * E_ + h * D_);

    float4 acc[4];
    #pragma unroll
    for (int j = 0; j < 4; ++j) acc[j] = make_float4(0.f, 0.f, 0.f, 0.f);
    float den = 0.f;

    #pragma unroll 4
    for (int jj = 0; jj < 16; ++jj) {
        const float4 a = qp[jj];
        const float p[4] = {sigk(a.x), sigk(a.y), sigk(a.z), sigk(a.w)};
        const int dbase = jj << 2;
        #pragma unroll
        for (int i = 0; i < 4; ++i) {
            const float s = p[i];
            den = fmaf(s, kvs[4096 + dbase + i], den);
            const float* krow = kvs + (size_t)(dbase + i) * 64 + el;
            #pragma unroll
            for (int j = 0; j < 4; ++j) {
                const float4 v = *(const float4*)(krow + (j << 4));
                acc[j].x = fmaf(s, v.x, acc[j].x);
                acc[j].y = fmaf(s, v.y, acc[j].y);
                acc[j].z = fmaf(s, v.z, acc[j].z);
                acc[j].w = fmaf(s, v.w, acc[j].w);
            }
        }
    }

    const float inv = __builtin_amdgcn_rcpf(den);
    float* op = out + ((size_t)b * L_ + row) * E_ + h * D_ + el;
    #pragma unroll
    for (int j = 0; j < 4; ++j) {
        float4 o;
        o.x = acc[j].x * inv; o.y = acc[j].y * inv;
        o.z = acc[j].z * inv; o.w = acc[j].w * inv;
        *(float4*)(op + (j << 4)) = o;
    }
}

extern "C" void kernel_launch(void* const* d_in, const int* in_sizes, int n_in,
                              void* d_out, int out_size, void* d_ws, size_t ws_size,
                              hipStream_t stream) {
    const float* Q = (const float*)d_in[0];
    const float* K = (const float*)d_in[1];
    const float* V = (const float*)d_in[2];
    float* out = (float*)d_out;

    float* kv      = (float*)d_ws;                 // BH_*STATE_ floats (~1 MiB)
    float* partial = kv + (size_t)BH_ * STATE_;    // NCH_*BH_*STATE_ floats

    hipLaunchKernelGGL(kv_partial_kernel, dim3(BH_ * NCH_), dim3(256), 0, stream,
                       K, V, partial);

    const int total = BH_ * STATE_;
    hipLaunchKernelGGL(kv_reduce_kernel, dim3((total + 255) / 256), dim3(256), 0, stream,
                       partial, kv);

    hipLaunchKernelGGL(attn_out_kernel, dim3(BH_ * (L_ / 64)), dim3(256), 0, stream,
                       Q, kv, out);
}